// Round 12
// baseline (120.479 us; speedup 1.0000x reference)
//
#include <hip/hip_runtime.h>

// ConvTranspose3d (2,64,32^3) fp32 -> (2,32,66^3), stride2 pad1 outpad1 dil2 k3.
// Odd-grid MFMA: out[n,co,2dp+1,2hp+1,2wp+1] = bias[co] +
//   sum_{ci,kd,kh,kw} x[n,ci,dp+1-kd,hp+1-kh,wp+1-kw] * w[ci,co,kd,kh,kw]
// R12: prep = w-pack + x16 im2col repack. convbias = conv blocks (DMA->LDS->
// MFMA, distributed split-K) writing FULL odd-od planes (no partial-line write
// amplification) interleaved with bias blocks covering even-od planes.

#define DOUT 66
#define PL (DOUT*DOUT)                  // 4356 floats/plane

typedef _Float16 half8 __attribute__((ext_vector_type(8)));
typedef float    floatx16 __attribute__((ext_vector_type(16)));

#define X16_N_F16  2228224              // f16 per n: 32*32*2176
#define ROW_B      4352                 // bytes per (id,ih) row: 8ccg*34iwl*8ci*2
#define ZSLAB_OFF  112640               // 8 KB zeros
#define X16_OFF    131072

#define PB_W    216                     // w-pack blocks
#define PB_X    512                     // x16 blocks
#define PREP_GRID (PB_W + PB_X)         // 728

#define NB_CONV 512
#define NB_BIAS 579                     // ceil(2369952 / 4096)
#define CB_GRID (NB_CONV + NB_BIAS)     // 1091

// ---- k1: prep = w-pack | x->f16 im2col layout ----
__global__ void __launch_bounds__(256) prep(
    const float* __restrict__ x, const float* __restrict__ w,
    _Float16* __restrict__ wA, _Float16* __restrict__ x16,
    uint4* __restrict__ zslab)
{
    const int tid = threadIdx.x;
    unsigned b = blockIdx.x;

    if (b < PB_W) {
        // wA[cc 4][tap 27][lane 64][8 f16]; lane=co+32*khalf, j->ci
        int o = b * 256 + tid;           // < 55296
        int j = o & 7;
        int tmp = o >> 3;
        int lane = tmp & 63;
        int g = tmp >> 6;                // cc*27 + tap
        int cc = g / 27, tap = g - cc * 27;
        int co = lane & 31, khalf = lane >> 5;
        int ci = cc * 16 + khalf * 8 + j;
        wA[o] = (_Float16)w[ci * 864 + co * 27 + tap];
        return;
    }
    b -= PB_W;
    {
        // x -> x16[n][id][ih][ccg 8][iwl 34][ci8 8]; halo zeroed
        const int id = b & 31;
        const int q2 = (b >> 5) & 7;     // 4-ih group
        const int n  = b >> 8;
        const int iw = tid & 31;
        const int cihalf = (tid >> 5) & 1;
        const int ihq = tid >> 6;        // 0..3
        const int ih = q2 * 4 + ihq;

        if (b == 0) {                    // zslab: 512 uint4 = 8 KB
            zslab[2 * tid]     = make_uint4(0, 0, 0, 0);
            zslab[2 * tid + 1] = make_uint4(0, 0, 0, 0);
        }

        const float* xr = x + (size_t)n * 2097152 + (id * 32 + ih) * 32 + iw;
        _Float16* drow = x16 + (size_t)n * X16_N_F16 + (id * 32 + ih) * 2176;
        const int c0 = cihalf * 32;

        float f[32];
        #pragma unroll
        for (int j = 0; j < 32; ++j) f[j] = xr[(size_t)(c0 + j) * 32768];
        #pragma unroll
        for (int k = 0; k < 4; ++k) {
            unsigned pk[4];
            #pragma unroll
            for (int j = 0; j < 4; ++j)
                pk[j] = __builtin_bit_cast(unsigned,
                    __builtin_amdgcn_cvt_pkrtz(f[8 * k + 2 * j], f[8 * k + 2 * j + 1]));
            const int ccg = cihalf * 4 + k;
            *(uint4*)(drow + ccg * 272 + (iw + 1) * 8) =
                make_uint4(pk[0], pk[1], pk[2], pk[3]);
        }
        // halo: 4 ih rows x 8 ccg x {iwl 0, 33} = 64 cells
        if (tid < 64) {
            const int ihq2 = tid >> 4;
            const int rem  = tid & 15;
            const int ccg  = rem >> 1, side = rem & 1;
            _Float16* hz = x16 + (size_t)n * X16_N_F16 +
                (id * 32 + q2 * 4 + ihq2) * 2176 + ccg * 272 + (side ? 264 : 0);
            *(uint4*)hz = make_uint4(0, 0, 0, 0);
        }
    }
}

// ---- k2: convbias — interleaved conv blocks + bias-a blocks ----
__global__ void __launch_bounds__(256, 2) convbias(
    const _Float16* __restrict__ x16, const _Float16* __restrict__ wA,
    const _Float16* __restrict__ zslab, const float* __restrict__ bias,
    float* __restrict__ out)
{
    __shared__ __align__(16) unsigned char xlds[78848];   // 18 rows x 4352 B (+pad)

    const int tid = threadIdx.x;
    unsigned b = blockIdx.x;

    // interleave: b<1024 -> even=conv(b/2), odd=bias(b/2); else bias(512+b-1024)
    bool is_conv;
    unsigned idx;
    if (b < 1024u) { is_conv = !(b & 1u); idx = b >> 1; }
    else           { is_conv = false;     idx = 512u + (b - 1024u); }

    if (!is_conv) {
        // ---- bias-a: full planes, od even (33) + od=65, float4 ----
        const unsigned base = idx * 4096u;
        #pragma unroll
        for (int j = 0; j < 16; ++j) {
            unsigned g = base + j * 256u + tid;
            if (g >= 2369952u) continue;             // 2*32*34*1089
            unsigned pl = g / 1089u;
            unsigned slot = g - pl * 1089u;
            unsigned e  = pl % 34u;
            unsigned nc = pl / 34u;
            unsigned od = (e < 33u) ? 2u * e : 65u;
            float v = bias[nc & 31u];
            float4* p = (float4*)(out + ((size_t)nc * DOUT + od) * PL);
            p[slot] = make_float4(v, v, v, v);
        }
        return;
    }

    // ---- conv block ----
    const int lane = tid & 63;
    const int wv   = tid >> 6;           // wave = K chunk AND output hp row

    const unsigned xcd = idx & 7u;
    const int n   = xcd & 1;
    const int dp  = (idx >> 3) & 31;
    const int hq  = idx >> 8;
    const int hpg = (int)(((xcd >> 1) << 1) | hq);        // 0..7
    const int hpb = hpg * 4;

    // B: async DMA rows -> LDS linear; invalid rows from zslab (FIRST)
    const char* xby = (const char*)(x16 + (size_t)n * X16_N_F16);
    const char* zby = (const char*)zslab;
    for (int m = wv; m < 77; m += 4) {   // 77 wave-instrs x 1024 B
        int c = m * 64 + lane;           // 16B chunk index
        int r = c / 272;
        int q = c - r * 272;
        const char* g;
        if (r < 18) {
            int idl = r / 6, ihl = r - idl * 6;
            int id = dp - 1 + idl, ih = hpb - 1 + ihl;
            bool v = ((unsigned)id < 32u) & ((unsigned)ih < 32u);
            g = v ? (xby + (id * 32 + ih) * ROW_B + q * 16) : (zby + q * 16);
        } else {
            g = zby;
        }
        __builtin_amdgcn_global_load_lds(
            (const __attribute__((address_space(1))) void*)g,
            (__attribute__((address_space(3))) void*)(xlds + m * 1024),
            16, 0, 0);
    }

    // A: 27 uint4 batch load (L2 latency hides under DMA transfer)
    uint4 A[27];
    const _Float16* wl = wA + ((size_t)wv * 27 * 64 + lane) * 8;
    #pragma unroll
    for (int t = 0; t < 27; ++t) A[t] = *(const uint4*)(wl + t * 512);

    __syncthreads();

    // K-loop: pure ds_read_b128 + MFMA, 4 independent acc chains
    const int wp    = lane & 31;
    const int khalf = lane >> 5;
    const int cbase = (2 * wv + khalf) * 544 + wp * 16;

    floatx16 acc[4] = {{}, {}, {}, {}};
    #pragma unroll
    for (int kd = 0; kd < 3; ++kd)
    #pragma unroll
    for (int kh = 0; kh < 3; ++kh)
    #pragma unroll
    for (int kw = 0; kw < 3; ++kw) {
        const int tap = (kd * 3 + kh) * 3 + kw;
        #pragma unroll
        for (int t = 0; t < 4; ++t) {
            const int row = (2 - kd) * 6 + (t + 2 - kh);
            const uint4* bp = (const uint4*)(xlds + row * ROW_B + cbase + (2 - kw) * 16);
            acc[t] = __builtin_amdgcn_mfma_f32_32x32x16_f16(
                __builtin_bit_cast(half8, A[tap]),
                __builtin_bit_cast(half8, *bp), acc[t], 0, 0, 0);
        }
    }

    // distributed split-K reduction through xlds
    __syncthreads();
    float* part = (float*)xlds;
    #pragma unroll
    for (int t = 0; t < 4; ++t) {
        if (t == wv) continue;
        #pragma unroll
        for (int r = 0; r < 16; ++r)
            part[((t * 4 + wv) * 16 + r) * 64 + lane] = acc[t][r];
    }
    __syncthreads();

    float s[16];
    #pragma unroll
    for (int r = 0; r < 16; ++r) s[r] = acc[wv][r];
    #pragma unroll
    for (int w2 = 0; w2 < 4; ++w2) {
        if (w2 == wv) continue;
        #pragma unroll
        for (int r = 0; r < 16; ++r)
            s[r] += part[((wv * 4 + w2) * 16 + r) * 64 + lane];
    }

    // stores: full plane coverage — odd oh (conv) + even oh (bias) per wave,
    // oh 64/65 tails from hpg7/wv3. No partial-line write amplification.
    const int od = 2 * dp + 1;
    const int hp = hpb + wv;
    const int oh_odd = 2 * hp + 1, oh_even = 2 * hp;
    const bool tails = (hpg == 7) && (wv == 3);
    #pragma unroll
    for (int r = 0; r < 16; ++r) {
        const int co = (r & 3) + 8 * (r >> 2) + 4 * khalf;   // verified C/D map
        const float bv = bias[co];
        float* pbase = out + ((size_t)(n * 32 + co) * DOUT + od) * PL;
        float2* orow = (float2*)(pbase + oh_odd * DOUT);
        float2* erow = (float2*)(pbase + oh_even * DOUT);
        orow[wp] = make_float2(bv, s[r] + bv);
        erow[wp] = make_float2(bv, bv);
        if (wp == 31) {
            orow[32] = make_float2(bv, bv);
            erow[32] = make_float2(bv, bv);
        }
        if (tails) {
            float2* t0 = (float2*)(pbase + 64 * DOUT);
            float2* t1 = (float2*)(pbase + 65 * DOUT);
            t0[wp] = make_float2(bv, bv);
            t1[wp] = make_float2(bv, bv);
            if (wp == 31) { t0[32] = make_float2(bv, bv); t1[32] = make_float2(bv, bv); }
        }
    }
}

extern "C" void kernel_launch(void* const* d_in, const int* in_sizes, int n_in,
                              void* d_out, int out_size, void* d_ws, size_t ws_size,
                              hipStream_t stream) {
    const float* x    = (const float*)d_in[0];
    const float* wgt  = (const float*)d_in[1];
    const float* bias = (const float*)d_in[2];
    float* out = (float*)d_out;
    _Float16* wA    = (_Float16*)d_ws;                    // [0, 110592)
    uint4*    zslab = (uint4*)((char*)d_ws + ZSLAB_OFF);  // 8 KB zeros
    _Float16* x16   = (_Float16*)((char*)d_ws + X16_OFF); // 8.9 MB

    prep<<<PREP_GRID, 256, 0, stream>>>(x, wgt, wA, x16, zslab);
    convbias<<<CB_GRID, 256, 0, stream>>>(x16, wA, (const _Float16*)zslab, bias, out);
}

// Round 13
// 108.968 us; speedup vs baseline: 1.1056x; 1.1056x over previous
//
#include <hip/hip_runtime.h>

// ConvTranspose3d (2,64,32^3) fp32 -> (2,32,66^3), stride2 pad1 outpad1 dil2 k3.
// Odd-grid MFMA: out[n,co,2dp+1,2hp+1,2wp+1] = bias[co] +
//   sum_{ci,kd,kh,kw} x[n,ci,dp+1-kd,hp+1-kh,wp+1-kw] * w[ci,co,kd,kh,kw]
// R13: prep (LDS-free: w-pack | x16 im2col repack | bias planes od-even+65)
// + standalone conv (2hp blocks, 52KB LDS, 3 blocks/CU for cross-generation
// pipelining; DMA->LDS->MFMA; distributed split-K; full odd-od plane writes).

#define DOUT 66
#define PL (DOUT*DOUT)                  // 4356 floats/plane

typedef _Float16 half8 __attribute__((ext_vector_type(8)));
typedef float    floatx16 __attribute__((ext_vector_type(16)));

#define X16_N_F16  2228224              // f16 per n: 32*32*2176
#define ROW_B      4352                 // bytes per (id,ih) row: 8ccg*34iwl*8ci*2
#define ZSLAB_OFF  112640               // 8 KB zeros
#define X16_OFF    131072

#define PB_W    216                     // w-pack blocks
#define PB_X    512                     // x16 blocks
#define PB_B    579                     // bias blocks (ceil(2369952/4096))
#define PREP_GRID (PB_W + PB_X + PB_B)  // 1307

// ---- k1: prep = w-pack | x16 repack | bias planes ----
__global__ void __launch_bounds__(256) prep(
    const float* __restrict__ x, const float* __restrict__ w,
    const float* __restrict__ bias, _Float16* __restrict__ wA,
    _Float16* __restrict__ x16, uint4* __restrict__ zslab,
    float* __restrict__ out)
{
    const int tid = threadIdx.x;
    unsigned b = blockIdx.x;

    if (b < PB_W) {
        // wA[cc 4][tap 27][lane 64][8 f16]; lane=co+32*khalf, j->ci
        int o = b * 256 + tid;           // < 55296
        int j = o & 7;
        int tmp = o >> 3;
        int lane = tmp & 63;
        int g = tmp >> 6;                // cc*27 + tap
        int cc = g / 27, tap = g - cc * 27;
        int co = lane & 31, khalf = lane >> 5;
        int ci = cc * 16 + khalf * 8 + j;
        wA[o] = (_Float16)w[ci * 864 + co * 27 + tap];
        return;
    }
    b -= PB_W;
    if (b < PB_X) {
        // x -> x16[n][id][ih][ccg 8][iwl 34][ci8 8]; halo zeroed
        const int id = b & 31;
        const int q2 = (b >> 5) & 7;     // 4-ih group
        const int n  = b >> 8;
        const int iw = tid & 31;
        const int cihalf = (tid >> 5) & 1;
        const int ihq = tid >> 6;        // 0..3
        const int ih = q2 * 4 + ihq;

        if (b == 0) {                    // zslab: 512 uint4 = 8 KB
            zslab[2 * tid]     = make_uint4(0, 0, 0, 0);
            zslab[2 * tid + 1] = make_uint4(0, 0, 0, 0);
        }

        const float* xr = x + (size_t)n * 2097152 + (id * 32 + ih) * 32 + iw;
        _Float16* drow = x16 + (size_t)n * X16_N_F16 + (id * 32 + ih) * 2176;
        const int c0 = cihalf * 32;

        float f[32];
        #pragma unroll
        for (int j = 0; j < 32; ++j) f[j] = xr[(size_t)(c0 + j) * 32768];
        #pragma unroll
        for (int k = 0; k < 4; ++k) {
            unsigned pk[4];
            #pragma unroll
            for (int j = 0; j < 4; ++j)
                pk[j] = __builtin_bit_cast(unsigned,
                    __builtin_amdgcn_cvt_pkrtz(f[8 * k + 2 * j], f[8 * k + 2 * j + 1]));
            const int ccg = cihalf * 4 + k;
            *(uint4*)(drow + ccg * 272 + (iw + 1) * 8) =
                make_uint4(pk[0], pk[1], pk[2], pk[3]);
        }
        // halo: 4 ih rows x 8 ccg x {iwl 0, 33}
        if (tid < 64) {
            const int ihq2 = tid >> 4;
            const int rem  = tid & 15;
            const int ccg  = rem >> 1, side = rem & 1;
            _Float16* hz = x16 + (size_t)n * X16_N_F16 +
                (id * 32 + q2 * 4 + ihq2) * 2176 + ccg * 272 + (side ? 264 : 0);
            *(uint4*)hz = make_uint4(0, 0, 0, 0);
        }
        return;
    }
    b -= PB_X;
    {
        // bias: full planes, od even (33) + od=65, float4 streaming
        const unsigned base = b * 4096u;
        #pragma unroll
        for (int j = 0; j < 16; ++j) {
            unsigned g = base + j * 256u + tid;
            if (g >= 2369952u) continue;             // 2*32*34*1089
            unsigned pl = g / 1089u;
            unsigned slot = g - pl * 1089u;
            unsigned e  = pl % 34u;
            unsigned nc = pl / 34u;
            unsigned od = (e < 33u) ? 2u * e : 65u;
            float v = bias[nc & 31u];
            float4* p = (float4*)(out + ((size_t)nc * DOUT + od) * PL);
            p[slot] = make_float4(v, v, v, v);
        }
    }
}

// ---- k2: conv — 2hp blocks, 3/CU, DMA-staged MFMA, distributed split-K ----
__global__ void __launch_bounds__(256, 3) convt(
    const _Float16* __restrict__ x16, const _Float16* __restrict__ wA,
    const _Float16* __restrict__ zslab, const float* __restrict__ bias,
    float* __restrict__ out)
{
    __shared__ __align__(16) unsigned char xlds[52224];   // 12 rows x 4352 B

    const int tid  = threadIdx.x;
    const int lane = tid & 63;
    const int wv   = tid >> 6;           // wave = K chunk (16 ci)

    unsigned b = blockIdx.x;             // 1024: xcd(3) | dp(5) | hq2(2)
    const unsigned xcd = b & 7u;
    const int n   = xcd & 1;
    const unsigned rest = b >> 3;
    const int dp  = rest & 31;
    const int hq2 = rest >> 5;           // 0..3
    const int hpg = (int)((xcd >> 1) * 4 + hq2);   // 0..15
    const int hpb = hpg * 2;             // hp0 = hpb, hp1 = hpb+1

    // ---- B: async DMA 12 rows (id 3 x ih 4) -> LDS; invalid rows from zslab ----
    const char* xby = (const char*)(x16 + (size_t)n * X16_N_F16);
    const char* zby = (const char*)zslab;
    for (int m = wv; m < 51; m += 4) {   // 51 x 1024 B = 52224 B
        int c = m * 64 + lane;           // 16B chunk index < 3264
        int r = c >> 8;                  // 3264/272: r = c/272
        r = c / 272;
        int q = c - r * 272;
        int idl = r >> 2, ihl = r & 3;
        int id = dp - 1 + idl, ih = hpb - 1 + ihl;
        bool v = ((unsigned)id < 32u) & ((unsigned)ih < 32u);
        const char* g = v ? (xby + (id * 32 + ih) * ROW_B + q * 16) : (zby + q * 16);
        __builtin_amdgcn_global_load_lds(
            (const __attribute__((address_space(1))) void*)g,
            (__attribute__((address_space(3))) void*)(xlds + m * 1024),
            16, 0, 0);
    }

    // ---- A: 27 uint4 batch load (hides under DMA transfer) ----
    uint4 A[27];
    const _Float16* wl = wA + ((size_t)wv * 27 * 64 + lane) * 8;
    #pragma unroll
    for (int t = 0; t < 27; ++t) A[t] = *(const uint4*)(wl + t * 512);

    __syncthreads();

    // ---- K-loop: 54 MFMAs (27 taps x 2 hp tiles), pure ds_read_b128 ----
    const int wp    = lane & 31;
    const int khalf = lane >> 5;
    const int cbase = (2 * wv + khalf) * 544 + wp * 16;

    floatx16 acc0 = {}, acc1 = {};
    #pragma unroll
    for (int kd = 0; kd < 3; ++kd)
    #pragma unroll
    for (int kh = 0; kh < 3; ++kh)
    #pragma unroll
    for (int kw = 0; kw < 3; ++kw) {
        const int tap = (kd * 3 + kh) * 3 + kw;
        const int row0 = (2 - kd) * 4 + (2 - kh);   // tile0; tile1 = row0+1
        const uint4* bp0 = (const uint4*)(xlds + row0 * ROW_B + cbase + (2 - kw) * 16);
        acc0 = __builtin_amdgcn_mfma_f32_32x32x16_f16(
            __builtin_bit_cast(half8, A[tap]),
            __builtin_bit_cast(half8, bp0[0]), acc0, 0, 0, 0);
        const uint4* bp1 = (const uint4*)((const char*)bp0 + ROW_B);
        acc1 = __builtin_amdgcn_mfma_f32_32x32x16_f16(
            __builtin_bit_cast(half8, A[tap]),
            __builtin_bit_cast(half8, bp1[0]), acc1, 0, 0, 0);
    }

    // ---- distributed split-K reduce: wave0 finalizes tile0, wave1 tile1 ----
    __syncthreads();
    float* part = (float*)xlds;          // part[(w*2+t)*16 + r][lane]
    if (wv != 0) {
        #pragma unroll
        for (int r = 0; r < 16; ++r)
            part[((wv * 2 + 0) * 16 + r) * 64 + lane] = acc0[r];
    }
    if (wv != 1) {
        #pragma unroll
        for (int r = 0; r < 16; ++r)
            part[((wv * 2 + 1) * 16 + r) * 64 + lane] = acc1[r];
    }
    __syncthreads();

    const int od = 2 * dp + 1;
    if (wv <= 1) {
        float s[16];
        #pragma unroll
        for (int r = 0; r < 16; ++r) {
            s[r] = (wv == 0) ? acc0[r] : acc1[r];
            #pragma unroll
            for (int w2 = 0; w2 < 4; ++w2) {
                if (w2 == wv) continue;
                s[r] += part[((w2 * 2 + wv) * 16 + r) * 64 + lane];
            }
        }
        const int oh = 2 * (hpb + wv) + 1;           // conv row
        #pragma unroll
        for (int r = 0; r < 16; ++r) {
            const int co = (r & 3) + 8 * (r >> 2) + 4 * khalf;   // verified C/D map
            const float bv = bias[co];
            float2* orow = (float2*)(out +
                ((size_t)(n * 32 + co) * DOUT + od) * PL + oh * DOUT);
            orow[wp] = make_float2(bv, s[r] + bv);
            if (wp == 31) orow[32] = make_float2(bv, bv);
        }
    } else {
        // even bias rows: wv2 -> oh=2hpb, wv3 -> oh=2hpb+2; tails at hpg15
        const int oh = (wv == 2) ? 2 * hpb : 2 * hpb + 2;
        const int oht = (wv == 2) ? 64 : 65;         // tail row if hpg15
        const bool tails = (hpg == 15);
        #pragma unroll
        for (int r = 0; r < 16; ++r) {
            const int co = (r & 3) + 8 * (r >> 2) + 4 * khalf;
            const float bv = bias[co];
            float* pbase = out + ((size_t)(n * 32 + co) * DOUT + od) * PL;
            float2* erow = (float2*)(pbase + oh * DOUT);
            erow[wp] = make_float2(bv, bv);
            if (wp == 31) erow[32] = make_float2(bv, bv);
            if (tails) {
                float2* trow = (float2*)(pbase + oht * DOUT);
                trow[wp] = make_float2(bv, bv);
                if (wp == 31) trow[32] = make_float2(bv, bv);
            }
        }
    }
}

extern "C" void kernel_launch(void* const* d_in, const int* in_sizes, int n_in,
                              void* d_out, int out_size, void* d_ws, size_t ws_size,
                              hipStream_t stream) {
    const float* x    = (const float*)d_in[0];
    const float* wgt  = (const float*)d_in[1];
    const float* bias = (const float*)d_in[2];
    float* out = (float*)d_out;
    _Float16* wA    = (_Float16*)d_ws;                    // [0, 110592)
    uint4*    zslab = (uint4*)((char*)d_ws + ZSLAB_OFF);  // 8 KB zeros
    _Float16* x16   = (_Float16*)((char*)d_ws + X16_OFF); // 8.9 MB

    prep<<<PREP_GRID, 256, 0, stream>>>(x, wgt, bias, wA, x16, zslab, out);
    convt<<<1024, 256, 0, stream>>>(x16, wA, (const _Float16*)zslab, bias, out);
}